// Round 9
// baseline (628.908 us; speedup 1.0000x reference)
//
#include <hip/hip_runtime.h>
#include <hip/hip_bf16.h>

#define NSUP 20
#define VEC 352
#define HID 352
#define GATES 1408
#define LIN 300
#define L1C 298
#define P1 59
#define L2C 57
#define P2 11
#define NBLK 2048   // grid for grid-stride stats/apply kernels

typedef __attribute__((ext_vector_type(8))) short short8v;
typedef __attribute__((ext_vector_type(4))) float float4v;

__device__ __forceinline__ float sigf(float x) { return 1.0f / (1.0f + __expf(-x)); }
// fast tanh: saturates to +/-1 at extremes without NaN; ~1e-6 rel err vs tanhf
__device__ __forceinline__ float ftanh(float x) { return 2.f / (1.f + __expf(-2.f * x)) - 1.f; }

__device__ __forceinline__ unsigned short f2bf(float x) {
    union { float f; unsigned u; } v; v.f = x;
    unsigned r = v.u + 0x7fffu + ((v.u >> 16) & 1u);
    return (unsigned short)(r >> 16);
}
__device__ __forceinline__ float bf2f(unsigned short s) {
    union { unsigned u; float f; } v; v.u = ((unsigned)s) << 16; return v.f;
}

// ---------------- cast weights to bf16, GATE-INTERLEAVED rows (row = h*4+g), + w2 transpose ----------------
__global__ __launch_bounds__(256) void cast_weights(
    const float* __restrict__ wihf, const float* __restrict__ wihr,
    const float* __restrict__ whhr, const float* __restrict__ w2,
    unsigned short* __restrict__ Wf, unsigned short* __restrict__ Wr,
    unsigned short* __restrict__ Wh, unsigned short* __restrict__ w2t)
{
    const int NW = GATES * VEC;
    int i = blockIdx.x * 256 + threadIdx.x;
    if (i < 3 * NW) {
        int m = i / NW, j = i - m * NW;
        int rr = j / VEC, k = j - rr * VEC;
        int h = rr >> 2, g = rr & 3;
        int src = (g * HID + h) * VEC + k;
        unsigned short v;
        const float* W = (m == 0) ? wihf : (m == 1) ? wihr : whhr;
        v = f2bf(W[src]);
        unsigned short* D = (m == 0) ? Wf : (m == 1) ? Wr : Wh;
        D[j] = v;
    } else if (i < 3 * NW + 5120) {
        int j = i - 3 * NW;
        int kk = j >> 10, c = (j >> 5) & 31, ci = j & 31;
        w2t[j] = f2bf(w2[c * 160 + ci * 5 + kk]);
    }
}

// ---------------- conv1: stats + pooled raw max -> h1 (bf16 [n][64][32], row=l+1) ----------------
__global__ __launch_bounds__(256) void conv1_pass1(const float* __restrict__ x,
    const float* __restrict__ w, const float* __restrict__ bias,
    float* __restrict__ part, unsigned short* __restrict__ h1, int N)
{
    int t = threadIdx.x;
    int wv = t >> 6, lane = t & 63;
    int c = lane & 31, half = lane >> 5;
    float wr[5];
#pragma unroll
    for (int k = 0; k < 5; ++k) wr[k] = w[c * 5 + k];
    float b = bias[c];
    float sum = 0.f, sq = 0.f;
    for (int n = blockIdx.x * 4 + wv; n < N; n += gridDim.x * 4) {
        const float* xr = x + (size_t)n * LIN;
        unsigned short* hr = h1 + (size_t)n * 2048;
        int b0 = half ? 8 : 0, b1 = half ? 15 : 8;
        for (int bb = b0; bb < b1; ++bb) {
            float xv[28];
            int base = bb * 20 - 4;
#pragma unroll
            for (int v8 = 0; v8 < 7; ++v8) {
                int bs = base + v8 * 4;
                if (bs >= 0 && bs + 3 < LIN) {
                    float4 q4 = *(const float4*)(xr + bs);
                    xv[v8 * 4 + 0] = q4.x; xv[v8 * 4 + 1] = q4.y;
                    xv[v8 * 4 + 2] = q4.z; xv[v8 * 4 + 3] = q4.w;
                } else {
#pragma unroll
                    for (int e = 0; e < 4; ++e) {
                        int ix = bs + e;
                        xv[v8 * 4 + e] = (ix >= 0 && ix < LIN) ? xr[ix] : 0.f;
                    }
                }
            }
#pragma unroll
            for (int grp = 0; grp < 4; ++grp) {
                int lo = bb * 4 + grp;
                float m = -1e30f;
#pragma unroll
                for (int d5 = 0; d5 < 5; ++d5) {
                    int dj = grp * 5 + d5;
                    int j = bb * 20 + dj;
                    if (j <= 297) {
                        float y = b;
#pragma unroll
                        for (int k = 0; k < 5; ++k) y = fmaf(wr[k], xv[dj + 3 + k], y);
                        sum += y; sq = fmaf(y, y, sq);
                        m = fmaxf(m, y);
                    }
                }
                if (lo <= 58) hr[(1 + lo) * 32 + c] = f2bf(m);
            }
        }
        if (half == 0) hr[c] = 0;
        else { hr[60 * 32 + c] = 0; hr[61 * 32 + c] = 0; hr[62 * 32 + c] = 0; hr[63 * 32 + c] = 0; }
    }
    __shared__ float redS[256], redQ[256];
    redS[t] = sum; redQ[t] = sq;
    __syncthreads();
    if (t < 32) {
        float s = 0.f, q = 0.f;
#pragma unroll
        for (int m = 0; m < 8; ++m) { s += redS[m * 32 + t]; q += redQ[m * 32 + t]; }
        part[blockIdx.x * 64 + t] = s;
        part[blockIdx.x * 64 + 32 + t] = q;
    }
}

// 512 threads: ch = t&63, grp = t>>6 (8 groups over NBLK blocks)
__global__ __launch_bounds__(512) void finalize_stats2(const float* __restrict__ part,
    float* __restrict__ outM, float* __restrict__ outI, float count)
{
    __shared__ float red[8][64];
    int t = threadIdx.x;
    int ch = t & 63, grp = t >> 6;
    float s = 0.f;
    for (int b = grp; b < NBLK; b += 8) s += part[b * 64 + ch];
    red[grp][ch] = s;
    __syncthreads();
    if (t < 64) {
        float a = 0.f;
#pragma unroll
        for (int g = 0; g < 8; ++g) a += red[g][t];
        red[0][t] = a;
    }
    __syncthreads();
    if (t < 32) {
        double m = (double)red[0][t] / (double)count;
        double v = (double)red[0][32 + t] / (double)count - m * m;
        outM[t] = (float)m;
        outI[t] = (float)(1.0 / sqrt(v + 1e-5));
    }
}

// ---------------- conv1 pass2: in-place BN+relu on pooled raw (rows 1..59) ----------------
__global__ __launch_bounds__(256) void conv1_pass2(unsigned short* __restrict__ h1,
    const float* __restrict__ mean, const float* __restrict__ istd,
    const float* __restrict__ g1, const float* __restrict__ b1n, long long total)
{
    __shared__ float sc[32], sh[32];
    int t = threadIdx.x;
    if (t < 32) { float s = istd[t] * g1[t]; sc[t] = s; sh[t] = b1n[t] - mean[t] * s; }
    __syncthreads();
    long long i = (long long)blockIdx.x * 256 + t;
    if (i >= total) return;
    long long n = i / 236; int r = (int)(i % 236);
    int row = 1 + (r >> 2), c0 = (r & 3) * 8;
    unsigned short* p = h1 + n * 2048 + row * 32 + c0;
    union { uint4 v; unsigned short u[8]; } d;
    d.v = *(const uint4*)p;
#pragma unroll
    for (int e = 0; e < 8; ++e) {
        int c = c0 + e;
        float y = fmaf(sc[c], bf2f(d.u[e]), sh[c]);
        d.u[e] = f2bf(fmaxf(y, 0.f));
    }
    *(uint4*)p = d.v;
}

// ---------------- conv2 stats via MFMA ----------------
__global__ __launch_bounds__(256) void conv2_stats_mfma(const unsigned short* __restrict__ h1,
    const unsigned short* __restrict__ w2t, const float* __restrict__ b2,
    float* __restrict__ part, int N)
{
    int t = threadIdx.x, wv = t >> 6, lane = t & 63;
    int li = lane & 15, grp = lane >> 4;
    short8v af[5][2];
#pragma unroll
    for (int kk = 0; kk < 5; ++kk)
#pragma unroll
        for (int mf = 0; mf < 2; ++mf)
            af[kk][mf] = *(const short8v*)(w2t + ((kk * 32 + mf * 16 + li) * 32 + grp * 8));
    float bc[2][4];
#pragma unroll
    for (int mf = 0; mf < 2; ++mf)
#pragma unroll
        for (int r = 0; r < 4; ++r) bc[mf][r] = b2[mf * 16 + grp * 4 + r];
    float sum[2][4] = {}, sq[2][4] = {};
    for (int n = blockIdx.x * 4 + wv; n < N; n += gridDim.x * 4) {
        const unsigned short* hb = h1 + (size_t)n * 2048;
#pragma unroll
        for (int lt = 0; lt < 4; ++lt) {
            float4v acc0 = {0.f, 0.f, 0.f, 0.f}, acc1 = {0.f, 0.f, 0.f, 0.f};
#pragma unroll
            for (int kk = 0; kk < 5; ++kk) {
                int row = lt * 16 + li + kk; row = row > 63 ? 63 : row;
                short8v bf = *(const short8v*)(hb + row * 32 + grp * 8);
                acc0 = __builtin_amdgcn_mfma_f32_16x16x32_bf16(af[kk][0], bf, acc0, 0, 0, 0);
                acc1 = __builtin_amdgcn_mfma_f32_16x16x32_bf16(af[kk][1], bf, acc1, 0, 0, 0);
            }
            if (lt * 16 + li < L2C) {
#pragma unroll
                for (int r = 0; r < 4; ++r) {
                    float y0 = acc0[r] + bc[0][r]; sum[0][r] += y0; sq[0][r] = fmaf(y0, y0, sq[0][r]);
                    float y1 = acc1[r] + bc[1][r]; sum[1][r] += y1; sq[1][r] = fmaf(y1, y1, sq[1][r]);
                }
            }
        }
    }
    __shared__ float redS[4][32], redQ[4][32];
#pragma unroll
    for (int mf = 0; mf < 2; ++mf)
#pragma unroll
        for (int r = 0; r < 4; ++r) {
            float s = sum[mf][r], q = sq[mf][r];
#pragma unroll
            for (int m = 1; m < 16; m <<= 1) { s += __shfl_xor(s, m); q += __shfl_xor(q, m); }
            if (li == 0) { redS[wv][mf * 16 + grp * 4 + r] = s; redQ[wv][mf * 16 + grp * 4 + r] = q; }
        }
    __syncthreads();
    if (t < 32) part[blockIdx.x * 64 + t] = redS[0][t] + redS[1][t] + redS[2][t] + redS[3][t];
    else if (t < 64) part[blockIdx.x * 64 + t] = redQ[0][t - 32] + redQ[1][t - 32] + redQ[2][t - 32] + redQ[3][t - 32];
}

// ---------------- conv2 apply via MFMA + BN + relu + pool -> z bf16 [n][352] ----------------
__global__ __launch_bounds__(256) void conv2_apply_mfma(const unsigned short* __restrict__ h1,
    const unsigned short* __restrict__ w2t, const float* __restrict__ b2,
    const float* __restrict__ mean, const float* __restrict__ istd,
    const float* __restrict__ g2, const float* __restrict__ be2,
    unsigned short* __restrict__ z, int N)
{
    __shared__ float yt[4][32][66];
    __shared__ float sc2[32], sh2[32], bcv[32];
    int t = threadIdx.x, wv = t >> 6, lane = t & 63;
    int li = lane & 15, grp = lane >> 4;
    if (t < 32) { float s = istd[t] * g2[t]; sc2[t] = s; sh2[t] = be2[t] - mean[t] * s; bcv[t] = b2[t]; }
    short8v af[5][2];
#pragma unroll
    for (int kk = 0; kk < 5; ++kk)
#pragma unroll
        for (int mf = 0; mf < 2; ++mf)
            af[kk][mf] = *(const short8v*)(w2t + ((kk * 32 + mf * 16 + li) * 32 + grp * 8));
    __syncthreads();
    for (int n = blockIdx.x * 4 + wv; n < N; n += gridDim.x * 4) {
        const unsigned short* hb = h1 + (size_t)n * 2048;
#pragma unroll
        for (int lt = 0; lt < 4; ++lt) {
            float4v acc0 = {0.f, 0.f, 0.f, 0.f}, acc1 = {0.f, 0.f, 0.f, 0.f};
#pragma unroll
            for (int kk = 0; kk < 5; ++kk) {
                int row = lt * 16 + li + kk; row = row > 63 ? 63 : row;
                short8v bf = *(const short8v*)(hb + row * 32 + grp * 8);
                acc0 = __builtin_amdgcn_mfma_f32_16x16x32_bf16(af[kk][0], bf, acc0, 0, 0, 0);
                acc1 = __builtin_amdgcn_mfma_f32_16x16x32_bf16(af[kk][1], bf, acc1, 0, 0, 0);
            }
#pragma unroll
            for (int r = 0; r < 4; ++r) {
                yt[wv][grp * 4 + r][lt * 16 + li] = acc0[r];
                yt[wv][16 + grp * 4 + r][lt * 16 + li] = acc1[r];
            }
        }
        unsigned short* zr = z + (size_t)n * VEC;
        for (int s = lane; s < VEC; s += 64) {
            int c = s / 11, lo = s % 11;
            float m = yt[wv][c][lo * 5];
#pragma unroll
            for (int d = 1; d < 5; ++d) m = fmaxf(m, yt[wv][c][lo * 5 + d]);
            float y = fmaf(sc2[c], m + bcv[c], sh2[c]);
            zr[s] = f2bf(fmaxf(y, 0.f));
        }
    }
}

// ---------------- support means ----------------
__global__ void sup_means(const unsigned short* __restrict__ z, float* __restrict__ misc)
{
    int v = blockIdx.x * 64 + threadIdx.x;
    if (v >= VEC) return;
    float s0 = 0.f, s1 = 0.f;
    for (int k = 0; k < 10; ++k) {
        s0 += bf2f(z[(size_t)k * VEC + v]);
        s1 += bf2f(z[(size_t)(10 + k) * VEC + v]);
    }
    misc[128 + v] = s0 * 0.1f;
    misc[480 + v] = s1 * 0.1f;
}

// ---------------- support-path gate GEMVs (fp32) ----------------
// misc layout (f32): 0 mean1,32 istd1,64 mean2,96 istd2,128 s0,480 s1,
// 832 h1f,1184 c1f,1536 h2f,1888 c2f, 2240 gtmp0(gate-major), 3648 gtmp1(gate-major),
// 5056 gf_const(ILV), 6464 pre_s1(ILV), 7872 pre_s0(ILV), 9280 br(ILV)
__global__ __launch_bounds__(128) void gates_gemv(int mode,
    const float* __restrict__ wihf, const float* __restrict__ whhf,
    const float* __restrict__ bihf, const float* __restrict__ bhhf,
    const float* __restrict__ wihr, const float* __restrict__ bihr,
    const float* __restrict__ bhhr, float* __restrict__ misc)
{
    __shared__ float s0[VEC], s1[VEC], h1f[VEC], h2f[VEC];
    int t = threadIdx.x;
    for (int i = t; i < VEC; i += 128) {
        s0[i] = misc[128 + i]; s1[i] = misc[480 + i];
        h1f[i] = misc[832 + i]; h2f[i] = misc[1536 + i];
    }
    __syncthreads();
    int j = blockIdx.x * 128 + t;
    if (j >= GATES) return;
    if (mode == 0) {
        float a = bihf[j] + bhhf[j];
        const float* w = wihf + (size_t)j * VEC;
        for (int k = 0; k < VEC; k += 4)
            a += w[k] * s0[k] + w[k + 1] * s0[k + 1] + w[k + 2] * s0[k + 2] + w[k + 3] * s0[k + 3];
        misc[2240 + j] = a;
    } else if (mode == 1) {
        float a = bihf[j] + bhhf[j];
        const float* w = wihf + (size_t)j * VEC;
        const float* wh = whhf + (size_t)j * VEC;
        for (int k = 0; k < VEC; k += 4) {
            a += w[k] * s1[k] + w[k + 1] * s1[k + 1] + w[k + 2] * s1[k + 2] + w[k + 3] * s1[k + 3];
            a += wh[k] * h1f[k] + wh[k + 1] * h1f[k + 1] + wh[k + 2] * h1f[k + 2] + wh[k + 3] * h1f[k + 3];
        }
        misc[3648 + j] = a;
    } else {
        int g = j / HID, h = j - g * HID;
        int jj = h * 4 + g;                     // interleaved index
        float a = bihf[j] + bhhf[j];
        const float* wh = whhf + (size_t)j * VEC;
        for (int k = 0; k < VEC; k += 4)
            a += wh[k] * h2f[k] + wh[k + 1] * h2f[k + 1] + wh[k + 2] * h2f[k + 2] + wh[k + 3] * h2f[k + 3];
        misc[5056 + jj] = a;                    // gf_const
        float br = bihr[j] + bhhr[j];
        misc[9280 + jj] = br;
        const float* wr = wihr + (size_t)j * VEC;
        float p1 = br, p0 = br;
        for (int k = 0; k < VEC; k += 4) {
            p1 += wr[k] * s1[k] + wr[k + 1] * s1[k + 1] + wr[k + 2] * s1[k + 2] + wr[k + 3] * s1[k + 3];
            p0 += wr[k] * s0[k] + wr[k + 1] * s0[k + 1] + wr[k + 2] * s0[k + 2] + wr[k + 3] * s0[k + 3];
        }
        misc[6464 + jj] = p1;                   // pre_s1
        misc[7872 + jj] = p0;                   // pre_s0
    }
}

__global__ void cell_small(const float* __restrict__ g, const float* __restrict__ cp,
    float* __restrict__ ho, float* __restrict__ co)
{
    int h = blockIdx.x * 64 + threadIdx.x;
    if (h >= HID) return;
    float iv = sigf(g[h]), fv = sigf(g[HID + h]);
    float gv = tanhf(g[2 * HID + h]), ov = sigf(g[3 * HID + h]);
    float c = iv * gv + (cp ? fv * cp[h] : 0.f);
    ho[h] = ov * tanhf(c);
    co[h] = c;
}

// ---------------- FUSED: all 4 big LSTM GEMM-steps + cells + cosine sims + softmax ----------------
// Block = 32 queries, 512 threads (8 waves). Wave w owns gate-interleaved W-rows [176w,176w+176):
// lane's 4 acc regs = (i,f,g,o) of one (q,h) -> cell is lane-local.
// Register plan: acc[2][11] in AGPRs (88); arch side: cst 22 + sums 18 + addr; hb1 NOT kept in
// regs (re-read lane-local bf16 from Blds); ks loops unroll 2, nt split 6/5 -> <=24-48 loads
// in flight. ftanh (exp-based) replaces ocml tanhf in epilogues.
__global__ __launch_bounds__(512) void lstm_fused(
    const unsigned short* __restrict__ zq,
    const unsigned short* __restrict__ Wf,
    const unsigned short* __restrict__ Wr,
    const unsigned short* __restrict__ Wh,
    const float* __restrict__ misc,
    float* __restrict__ out, int Q)
{
    __shared__ unsigned short Alds[32][360];
    __shared__ unsigned short Blds[32][360];
    __shared__ float red[8][32][10];
    int t = threadIdx.x;
    int w = t >> 6, lane = t & 63;
    int li = lane & 15, grp = lane >> 4;
    int q0 = blockIdx.x * 32;

    // stage zq tile (32 x 352 bf16) into Alds: 44 chunks of 8 bf16 (16B) per row
    for (int i = t; i < 32 * 44; i += 512) {
        int r = i / 44, ch = i - r * 44;
        int qr = q0 + r; if (qr > Q - 1) qr = Q - 1;
        *(uint4*)&Alds[r][ch * 8] = *(const uint4*)(zq + (size_t)qr * VEC + ch * 8);
    }

    const int wbase0 = (w * 176 + li) * VEC + grp * 8;
    const int hcol = w * 44 + grp;             // + nt*4
    float4v acc[2][11];
    float cst[2][11];
    float s3[2] = {0.f, 0.f}, sA[2] = {0.f, 0.f}, sB[2] = {0.f, 0.f}, s4[2] = {0.f, 0.f};
    float s8[2] = {0.f, 0.f}, s6[2] = {0.f, 0.f}, s7[2] = {0.f, 0.f}, s5[2] = {0.f, 0.f};
    float s9 = 0.f, s10 = 0.f;

    __syncthreads();

#define GEMM_PART(WPTR, BUF, NTA, NTB) \
    _Pragma("unroll 2") for (int ks = 0; ks < 11; ++ks) { \
        short8v x0 = *(const short8v*)&BUF[li][ks * 32 + grp * 8]; \
        short8v x1 = *(const short8v*)&BUF[16 + li][ks * 32 + grp * 8]; \
        _Pragma("unroll") for (int nt = (NTA); nt < (NTB); ++nt) { \
            short8v wvv = *(const short8v*)((WPTR) + (size_t)(wbase0 + nt * 5632 + ks * 32)); \
            acc[0][nt] = __builtin_amdgcn_mfma_f32_16x16x32_bf16(wvv, x0, acc[0][nt], 0, 0, 0); \
            acc[1][nt] = __builtin_amdgcn_mfma_f32_16x16x32_bf16(wvv, x1, acc[1][nt], 0, 0, 0); \
        } \
    }

#define GEMM(WPTR, BUF) \
    _Pragma("unroll") for (int qt = 0; qt < 2; ++qt) \
    _Pragma("unroll") for (int nt = 0; nt < 11; ++nt) acc[qt][nt] = (float4v){0.f, 0.f, 0.f, 0.f}; \
    GEMM_PART(WPTR, BUF, 0, 6) \
    GEMM_PART(WPTR, BUF, 6, 11)

    // ---- forward step 2: gates = zq@Wf + gf_const ; cprev = c2f ----
    GEMM(Wf, Alds);
#pragma unroll
    for (int nt = 0; nt < 11; ++nt) {
        int h = hcol + nt * 4;
        float4 ad = *(const float4*)&misc[5056 + w * 176 + nt * 16 + grp * 4];
        float c2 = misc[1888 + h], h1c = misc[832 + h], h2c = misc[1536 + h];
        s9 = fmaf(h1c, h1c, s9);
        s10 = fmaf(h2c, h2c, s10);
#pragma unroll
        for (int qt = 0; qt < 2; ++qt) {
            float iv = sigf(acc[qt][nt][0] + ad.x);
            float fv = sigf(acc[qt][nt][1] + ad.y);
            float gv = ftanh(acc[qt][nt][2] + ad.z);
            float ov = sigf(acc[qt][nt][3] + ad.w);
            float cn = fmaf(fv, c2, iv * gv);
            float hn = ov * ftanh(cn);
            s3[qt] = fmaf(hn, hn, s3[qt]);
            sA[qt] = fmaf(h1c, hn, sA[qt]);
            sB[qt] = fmaf(h2c, hn, sB[qt]);
        }
    }

    // ---- backward step 0: gates = zq@Wr + br ; cprev = 0 ; write hb1 -> Blds ----
    GEMM(Wr, Alds);
#pragma unroll
    for (int nt = 0; nt < 11; ++nt) {
        float4 ad = *(const float4*)&misc[9280 + w * 176 + nt * 16 + grp * 4];
#pragma unroll
        for (int qt = 0; qt < 2; ++qt) {
            float iv = sigf(acc[qt][nt][0] + ad.x);
            float gv = ftanh(acc[qt][nt][2] + ad.z);
            float ov = sigf(acc[qt][nt][3] + ad.w);
            float cn = iv * gv;
            float hn = ov * ftanh(cn);
            cst[qt][nt] = cn;
            s4[qt] = fmaf(hn, hn, s4[qt]);
            Blds[qt * 16 + li][hcol + nt * 4] = f2bf(hn);
        }
    }
    __syncthreads();

    // ---- backward step 1: gates = hb1@Wh + pre_s1 ; write hb2 -> Alds (zq dead) ----
    GEMM(Wh, Blds);
#pragma unroll
    for (int nt = 0; nt < 11; ++nt) {
        float4 ad = *(const float4*)&misc[6464 + w * 176 + nt * 16 + grp * 4];
#pragma unroll
        for (int qt = 0; qt < 2; ++qt) {
            float iv = sigf(acc[qt][nt][0] + ad.x);
            float fv = sigf(acc[qt][nt][1] + ad.y);
            float gv = ftanh(acc[qt][nt][2] + ad.z);
            float ov = sigf(acc[qt][nt][3] + ad.w);
            float cn = fmaf(fv, cst[qt][nt], iv * gv);
            float hn = ov * ftanh(cn);
            cst[qt][nt] = cn;
            float h1b = bf2f(Blds[qt * 16 + li][hcol + nt * 4]);   // lane-local hb1 (bf16)
            s8[qt] = fmaf(hn, hn, s8[qt]);
            s6[qt] = fmaf(hn, h1b, s6[qt]);
            Alds[qt * 16 + li][hcol + nt * 4] = f2bf(hn);
        }
    }
    __syncthreads();

    // ---- backward step 2: gates = hb2@Wh + pre_s0 ----
    GEMM(Wh, Alds);
#pragma unroll
    for (int nt = 0; nt < 11; ++nt) {
        float4 ad = *(const float4*)&misc[7872 + w * 176 + nt * 16 + grp * 4];
#pragma unroll
        for (int qt = 0; qt < 2; ++qt) {
            float iv = sigf(acc[qt][nt][0] + ad.x);
            float fv = sigf(acc[qt][nt][1] + ad.y);
            float gv = ftanh(acc[qt][nt][2] + ad.z);
            float ov = sigf(acc[qt][nt][3] + ad.w);
            float cn = fmaf(fv, cst[qt][nt], iv * gv);
            float hn = ov * ftanh(cn);
            float h1b = bf2f(Blds[qt * 16 + li][hcol + nt * 4]);   // lane-local hb1 (bf16)
            s7[qt] = fmaf(hn, hn, s7[qt]);
            s5[qt] = fmaf(hn, h1b, s5[qt]);
        }
    }

    // ---- reduction: per-q sums over h (grp bits within wave, then waves via LDS) ----
#define RED1(EXPR, S) { float v = (EXPR); v += __shfl_xor(v, 16); v += __shfl_xor(v, 32); \
                        if (grp == 0) red[w][qt * 16 + li][S] = v; }
#pragma unroll
    for (int qt = 0; qt < 2; ++qt) {
        RED1(s3[qt], 0) RED1(sA[qt], 1) RED1(sB[qt], 2) RED1(s4[qt], 3)
        RED1(s8[qt], 4) RED1(s6[qt], 5) RED1(s7[qt], 6) RED1(s5[qt], 7)
        RED1(s9, 8) RED1(s10, 9)
    }
    __syncthreads();
    if (t < 32) {
        int q = q0 + t;
        if (q < Q) {
            float s[10];
#pragma unroll
            for (int k = 0; k < 10; ++k) {
                float a = 0.f;
#pragma unroll
                for (int ww = 0; ww < 8; ++ww) a += red[ww][t][k];
                s[k] = a;
            }
            float nq  = fmaxf(sqrtf(s[0] + s[3]), 1e-8f);
            float ns0 = fmaxf(sqrtf(s[8] + s[6]), 1e-8f);
            float ns1 = fmaxf(sqrtf(s[9] + s[4]), 1e-8f);
            float sim0 = (s[1] + s[7]) / (ns0 * nq);
            float sim1 = (s[2] + s[5]) / (ns1 * nq);
            float mx = fmaxf(sim0, sim1);
            float e0 = __expf(sim0 - mx), e1 = __expf(sim1 - mx);
            float inv = 1.f / (e0 + e1);
            out[(size_t)q * 2 + 0] = e0 * inv;
            out[(size_t)q * 2 + 1] = e1 * inv;
        }
    }
#undef GEMM
#undef GEMM_PART
#undef RED1
}

extern "C" void kernel_launch(void* const* d_in, const int* in_sizes, int n_in,
                              void* d_out, int out_size, void* d_ws, size_t ws_size,
                              hipStream_t stream)
{
    const float* x    = (const float*)d_in[0];
    const float* c1w  = (const float*)d_in[1];
    const float* c1b  = (const float*)d_in[2];
    const float* bn1g = (const float*)d_in[3];
    const float* bn1b = (const float*)d_in[4];
    const float* c2w  = (const float*)d_in[5];
    const float* c2b  = (const float*)d_in[6];
    const float* bn2g = (const float*)d_in[7];
    const float* bn2b = (const float*)d_in[8];
    const float* wihf = (const float*)d_in[9];
    const float* whhf = (const float*)d_in[10];
    const float* bihf = (const float*)d_in[11];
    const float* bhhf = (const float*)d_in[12];
    const float* wihr = (const float*)d_in[13];
    const float* whhr = (const float*)d_in[14];
    const float* bihr = (const float*)d_in[15];
    const float* bhhr = (const float*)d_in[16];

    int N = in_sizes[0] / LIN;
    int Q = N - NSUP;

    char* ws = (char*)d_ws;
    float* part1 = (float*)(ws + 0);                       // 2048*64 f32
    float* part2 = (float*)(ws + 524288);
    float* misc  = (float*)(ws + 1048576);                 // ~10.7K f32
    unsigned short* w2t = (unsigned short*)(ws + 1114112); // 5120 bf16
    unsigned short* Wf  = (unsigned short*)(ws + 2097152); // 1408*352 bf16 interleaved
    unsigned short* Wr  = (unsigned short*)(ws + 3145728);
    unsigned short* Wh  = (unsigned short*)(ws + 4194304);
    unsigned short* z   = (unsigned short*)(ws + 5242880); // N*352 bf16
    unsigned short* h1  = (unsigned short*)(ws + 17825792);// N*64*32 bf16

    // 1. cast + interleave weights
    {
        int tot = 3 * GATES * VEC + 5120;
        cast_weights<<<(tot + 255) / 256, 256, 0, stream>>>(wihf, wihr, whhr, c2w, Wf, Wr, Wh, w2t);
    }
    // 2. conv1: stats + pooled raw
    conv1_pass1<<<NBLK, 256, 0, stream>>>(x, c1w, c1b, part1, h1, N);
    finalize_stats2<<<1, 512, 0, stream>>>(part1, misc + 0, misc + 32, (float)((long long)N * L1C));
    // 3. conv1 BN+relu in place
    {
        long long total = (long long)N * 236;
        conv1_pass2<<<(unsigned)((total + 255) / 256), 256, 0, stream>>>(h1, misc + 0, misc + 32, bn1g, bn1b, total);
    }
    // 4. conv2 stats
    conv2_stats_mfma<<<NBLK, 256, 0, stream>>>(h1, w2t, c2b, part2, N);
    finalize_stats2<<<1, 512, 0, stream>>>(part2, misc + 64, misc + 96, (float)((long long)N * L2C));
    // 5. conv2 apply -> z
    conv2_apply_mfma<<<NBLK, 256, 0, stream>>>(h1, w2t, c2b, misc + 64, misc + 96, bn2g, bn2b, z, N);
    // 6. support path
    sup_means<<<6, 64, 0, stream>>>(z, misc);
    gates_gemv<<<11, 128, 0, stream>>>(0, wihf, whhf, bihf, bhhf, wihr, bihr, bhhr, misc);
    cell_small<<<6, 64, 0, stream>>>(misc + 2240, nullptr, misc + 832, misc + 1184);
    gates_gemv<<<11, 128, 0, stream>>>(1, wihf, whhf, bihf, bhhf, wihr, bihr, bhhr, misc);
    cell_small<<<6, 64, 0, stream>>>(misc + 3648, misc + 1184, misc + 1536, misc + 1888);
    gates_gemv<<<11, 128, 0, stream>>>(2, wihf, whhf, bihf, bhhf, wihr, bihr, bhhr, misc);
    // 7. fused LSTM + sims + softmax
    const unsigned short* zq = z + (size_t)NSUP * VEC;
    lstm_fused<<<(Q + 31) / 32, 512, 0, stream>>>(zq, Wf, Wr, Wh, misc, (float*)d_out, Q);
}

// Round 10
// 536.741 us; speedup vs baseline: 1.1717x; 1.1717x over previous
//
#include <hip/hip_runtime.h>
#include <hip/hip_bf16.h>

#define NSUP 20
#define VEC 352
#define HID 352
#define GATES 1408
#define LIN 300
#define L1C 298
#define P1 59
#define L2C 57
#define P2 11
#define NBLK 2048   // grid for grid-stride stats/apply kernels

typedef __attribute__((ext_vector_type(8))) short short8v;
typedef __attribute__((ext_vector_type(4))) float float4v;

__device__ __forceinline__ float sigf(float x) { return 1.0f / (1.0f + __expf(-x)); }
// fast tanh: saturates to +/-1 at extremes without NaN; ~1e-6 rel err vs tanhf
__device__ __forceinline__ float ftanh(float x) { return 2.f / (1.f + __expf(-2.f * x)) - 1.f; }

__device__ __forceinline__ unsigned short f2bf(float x) {
    union { float f; unsigned u; } v; v.f = x;
    unsigned r = v.u + 0x7fffu + ((v.u >> 16) & 1u);
    return (unsigned short)(r >> 16);
}
__device__ __forceinline__ float bf2f(unsigned short s) {
    union { unsigned u; float f; } v; v.u = ((unsigned)s) << 16; return v.f;
}

// ---------------- cast weights to bf16 (plain row-major copies) + w2 transpose ----------------
__global__ __launch_bounds__(256) void cast_weights(
    const float* __restrict__ wihf, const float* __restrict__ wihr,
    const float* __restrict__ whhr, const float* __restrict__ w2,
    unsigned short* __restrict__ Wf, unsigned short* __restrict__ Wr,
    unsigned short* __restrict__ Wh, unsigned short* __restrict__ w2t)
{
    const int NW = GATES * VEC;
    int i = blockIdx.x * 256 + threadIdx.x;
    if (i < NW) Wf[i] = f2bf(wihf[i]);
    else if (i < 2 * NW) Wr[i - NW] = f2bf(wihr[i - NW]);
    else if (i < 3 * NW) Wh[i - 2 * NW] = f2bf(whhr[i - 2 * NW]);
    else if (i < 3 * NW + 5120) {
        int j = i - 3 * NW;
        int kk = j >> 10, c = (j >> 5) & 31, ci = j & 31;
        w2t[j] = f2bf(w2[c * 160 + ci * 5 + kk]);
    }
}

// ---------------- conv1: stats + pooled raw max -> h1 (bf16 [n][64][32], row=l+1) ----------------
__global__ __launch_bounds__(256) void conv1_pass1(const float* __restrict__ x,
    const float* __restrict__ w, const float* __restrict__ bias,
    float* __restrict__ part, unsigned short* __restrict__ h1, int N)
{
    int t = threadIdx.x;
    int wv = t >> 6, lane = t & 63;
    int c = lane & 31, half = lane >> 5;
    float wr[5];
#pragma unroll
    for (int k = 0; k < 5; ++k) wr[k] = w[c * 5 + k];
    float b = bias[c];
    float sum = 0.f, sq = 0.f;
    for (int n = blockIdx.x * 4 + wv; n < N; n += gridDim.x * 4) {
        const float* xr = x + (size_t)n * LIN;
        unsigned short* hr = h1 + (size_t)n * 2048;
        int b0 = half ? 8 : 0, b1 = half ? 15 : 8;
        for (int bb = b0; bb < b1; ++bb) {
            float xv[28];
            int base = bb * 20 - 4;
#pragma unroll
            for (int v8 = 0; v8 < 7; ++v8) {
                int bs = base + v8 * 4;
                if (bs >= 0 && bs + 3 < LIN) {
                    float4 q4 = *(const float4*)(xr + bs);
                    xv[v8 * 4 + 0] = q4.x; xv[v8 * 4 + 1] = q4.y;
                    xv[v8 * 4 + 2] = q4.z; xv[v8 * 4 + 3] = q4.w;
                } else {
#pragma unroll
                    for (int e = 0; e < 4; ++e) {
                        int ix = bs + e;
                        xv[v8 * 4 + e] = (ix >= 0 && ix < LIN) ? xr[ix] : 0.f;
                    }
                }
            }
#pragma unroll
            for (int grp = 0; grp < 4; ++grp) {
                int lo = bb * 4 + grp;
                float m = -1e30f;
#pragma unroll
                for (int d5 = 0; d5 < 5; ++d5) {
                    int dj = grp * 5 + d5;
                    int j = bb * 20 + dj;
                    if (j <= 297) {
                        float y = b;
#pragma unroll
                        for (int k = 0; k < 5; ++k) y = fmaf(wr[k], xv[dj + 3 + k], y);
                        sum += y; sq = fmaf(y, y, sq);
                        m = fmaxf(m, y);
                    }
                }
                if (lo <= 58) hr[(1 + lo) * 32 + c] = f2bf(m);
            }
        }
        if (half == 0) hr[c] = 0;
        else { hr[60 * 32 + c] = 0; hr[61 * 32 + c] = 0; hr[62 * 32 + c] = 0; hr[63 * 32 + c] = 0; }
    }
    __shared__ float redS[256], redQ[256];
    redS[t] = sum; redQ[t] = sq;
    __syncthreads();
    if (t < 32) {
        float s = 0.f, q = 0.f;
#pragma unroll
        for (int m = 0; m < 8; ++m) { s += redS[m * 32 + t]; q += redQ[m * 32 + t]; }
        part[blockIdx.x * 64 + t] = s;
        part[blockIdx.x * 64 + 32 + t] = q;
    }
}

// 512 threads: ch = t&63, grp = t>>6 (8 groups over NBLK blocks)
__global__ __launch_bounds__(512) void finalize_stats2(const float* __restrict__ part,
    float* __restrict__ outM, float* __restrict__ outI, float count)
{
    __shared__ float red[8][64];
    int t = threadIdx.x;
    int ch = t & 63, grp = t >> 6;
    float s = 0.f;
    for (int b = grp; b < NBLK; b += 8) s += part[b * 64 + ch];
    red[grp][ch] = s;
    __syncthreads();
    if (t < 64) {
        float a = 0.f;
#pragma unroll
        for (int g = 0; g < 8; ++g) a += red[g][t];
        red[0][t] = a;
    }
    __syncthreads();
    if (t < 32) {
        double m = (double)red[0][t] / (double)count;
        double v = (double)red[0][32 + t] / (double)count - m * m;
        outM[t] = (float)m;
        outI[t] = (float)(1.0 / sqrt(v + 1e-5));
    }
}

// ---------------- conv1 pass2: in-place BN+relu on pooled raw (rows 1..59) ----------------
__global__ __launch_bounds__(256) void conv1_pass2(unsigned short* __restrict__ h1,
    const float* __restrict__ mean, const float* __restrict__ istd,
    const float* __restrict__ g1, const float* __restrict__ b1n, long long total)
{
    __shared__ float sc[32], sh[32];
    int t = threadIdx.x;
    if (t < 32) { float s = istd[t] * g1[t]; sc[t] = s; sh[t] = b1n[t] - mean[t] * s; }
    __syncthreads();
    long long i = (long long)blockIdx.x * 256 + t;
    if (i >= total) return;
    long long n = i / 236; int r = (int)(i % 236);
    int row = 1 + (r >> 2), c0 = (r & 3) * 8;
    unsigned short* p = h1 + n * 2048 + row * 32 + c0;
    union { uint4 v; unsigned short u[8]; } d;
    d.v = *(const uint4*)p;
#pragma unroll
    for (int e = 0; e < 8; ++e) {
        int c = c0 + e;
        float y = fmaf(sc[c], bf2f(d.u[e]), sh[c]);
        d.u[e] = f2bf(fmaxf(y, 0.f));
    }
    *(uint4*)p = d.v;
}

// ---------------- conv2 stats via MFMA ----------------
__global__ __launch_bounds__(256) void conv2_stats_mfma(const unsigned short* __restrict__ h1,
    const unsigned short* __restrict__ w2t, const float* __restrict__ b2,
    float* __restrict__ part, int N)
{
    int t = threadIdx.x, wv = t >> 6, lane = t & 63;
    int li = lane & 15, grp = lane >> 4;
    short8v af[5][2];
#pragma unroll
    for (int kk = 0; kk < 5; ++kk)
#pragma unroll
        for (int mf = 0; mf < 2; ++mf)
            af[kk][mf] = *(const short8v*)(w2t + ((kk * 32 + mf * 16 + li) * 32 + grp * 8));
    float bc[2][4];
#pragma unroll
    for (int mf = 0; mf < 2; ++mf)
#pragma unroll
        for (int r = 0; r < 4; ++r) bc[mf][r] = b2[mf * 16 + grp * 4 + r];
    float sum[2][4] = {}, sq[2][4] = {};
    for (int n = blockIdx.x * 4 + wv; n < N; n += gridDim.x * 4) {
        const unsigned short* hb = h1 + (size_t)n * 2048;
#pragma unroll
        for (int lt = 0; lt < 4; ++lt) {
            float4v acc0 = {0.f, 0.f, 0.f, 0.f}, acc1 = {0.f, 0.f, 0.f, 0.f};
#pragma unroll
            for (int kk = 0; kk < 5; ++kk) {
                int row = lt * 16 + li + kk; row = row > 63 ? 63 : row;
                short8v bf = *(const short8v*)(hb + row * 32 + grp * 8);
                acc0 = __builtin_amdgcn_mfma_f32_16x16x32_bf16(af[kk][0], bf, acc0, 0, 0, 0);
                acc1 = __builtin_amdgcn_mfma_f32_16x16x32_bf16(af[kk][1], bf, acc1, 0, 0, 0);
            }
            if (lt * 16 + li < L2C) {
#pragma unroll
                for (int r = 0; r < 4; ++r) {
                    float y0 = acc0[r] + bc[0][r]; sum[0][r] += y0; sq[0][r] = fmaf(y0, y0, sq[0][r]);
                    float y1 = acc1[r] + bc[1][r]; sum[1][r] += y1; sq[1][r] = fmaf(y1, y1, sq[1][r]);
                }
            }
        }
    }
    __shared__ float redS[4][32], redQ[4][32];
#pragma unroll
    for (int mf = 0; mf < 2; ++mf)
#pragma unroll
        for (int r = 0; r < 4; ++r) {
            float s = sum[mf][r], q = sq[mf][r];
#pragma unroll
            for (int m = 1; m < 16; m <<= 1) { s += __shfl_xor(s, m); q += __shfl_xor(q, m); }
            if (li == 0) { redS[wv][mf * 16 + grp * 4 + r] = s; redQ[wv][mf * 16 + grp * 4 + r] = q; }
        }
    __syncthreads();
    if (t < 32) part[blockIdx.x * 64 + t] = redS[0][t] + redS[1][t] + redS[2][t] + redS[3][t];
    else if (t < 64) part[blockIdx.x * 64 + t] = redQ[0][t - 32] + redQ[1][t - 32] + redQ[2][t - 32] + redQ[3][t - 32];
}

// ---------------- conv2 apply via MFMA + BN + relu + pool -> z bf16 [n][352] ----------------
__global__ __launch_bounds__(256) void conv2_apply_mfma(const unsigned short* __restrict__ h1,
    const unsigned short* __restrict__ w2t, const float* __restrict__ b2,
    const float* __restrict__ mean, const float* __restrict__ istd,
    const float* __restrict__ g2, const float* __restrict__ be2,
    unsigned short* __restrict__ z, int N)
{
    __shared__ float yt[4][32][66];
    __shared__ float sc2[32], sh2[32], bcv[32];
    int t = threadIdx.x, wv = t >> 6, lane = t & 63;
    int li = lane & 15, grp = lane >> 4;
    if (t < 32) { float s = istd[t] * g2[t]; sc2[t] = s; sh2[t] = be2[t] - mean[t] * s; bcv[t] = b2[t]; }
    short8v af[5][2];
#pragma unroll
    for (int kk = 0; kk < 5; ++kk)
#pragma unroll
        for (int mf = 0; mf < 2; ++mf)
            af[kk][mf] = *(const short8v*)(w2t + ((kk * 32 + mf * 16 + li) * 32 + grp * 8));
    __syncthreads();
    for (int n = blockIdx.x * 4 + wv; n < N; n += gridDim.x * 4) {
        const unsigned short* hb = h1 + (size_t)n * 2048;
#pragma unroll
        for (int lt = 0; lt < 4; ++lt) {
            float4v acc0 = {0.f, 0.f, 0.f, 0.f}, acc1 = {0.f, 0.f, 0.f, 0.f};
#pragma unroll
            for (int kk = 0; kk < 5; ++kk) {
                int row = lt * 16 + li + kk; row = row > 63 ? 63 : row;
                short8v bf = *(const short8v*)(hb + row * 32 + grp * 8);
                acc0 = __builtin_amdgcn_mfma_f32_16x16x32_bf16(af[kk][0], bf, acc0, 0, 0, 0);
                acc1 = __builtin_amdgcn_mfma_f32_16x16x32_bf16(af[kk][1], bf, acc1, 0, 0, 0);
            }
#pragma unroll
            for (int r = 0; r < 4; ++r) {
                yt[wv][grp * 4 + r][lt * 16 + li] = acc0[r];
                yt[wv][16 + grp * 4 + r][lt * 16 + li] = acc1[r];
            }
        }
        unsigned short* zr = z + (size_t)n * VEC;
        for (int s = lane; s < VEC; s += 64) {
            int c = s / 11, lo = s % 11;
            float m = yt[wv][c][lo * 5];
#pragma unroll
            for (int d = 1; d < 5; ++d) m = fmaxf(m, yt[wv][c][lo * 5 + d]);
            float y = fmaf(sc2[c], m + bcv[c], sh2[c]);
            zr[s] = f2bf(fmaxf(y, 0.f));
        }
    }
}

// ---------------- support means ----------------
__global__ void sup_means(const unsigned short* __restrict__ z, float* __restrict__ misc)
{
    int v = blockIdx.x * 64 + threadIdx.x;
    if (v >= VEC) return;
    float s0 = 0.f, s1 = 0.f;
    for (int k = 0; k < 10; ++k) {
        s0 += bf2f(z[(size_t)k * VEC + v]);
        s1 += bf2f(z[(size_t)(10 + k) * VEC + v]);
    }
    misc[128 + v] = s0 * 0.1f;
    misc[480 + v] = s1 * 0.1f;
}

// ---------------- support-path gate GEMVs (fp32) ----------------
// misc layout (f32): 0 mean1,32 istd1,64 mean2,96 istd2,128 s0,480 s1,
// 832 h1f,1184 c1f,1536 h2f,1888 c2f, 2240 gtmp0, 3648 gtmp1,
// 5056 gf_const, 6464 pre_s1, 7872 pre_s0   (all gate-major)
__global__ __launch_bounds__(128) void gates_gemv(int mode,
    const float* __restrict__ wihf, const float* __restrict__ whhf,
    const float* __restrict__ bihf, const float* __restrict__ bhhf,
    const float* __restrict__ wihr, const float* __restrict__ bihr,
    const float* __restrict__ bhhr, float* __restrict__ misc)
{
    __shared__ float s0[VEC], s1[VEC], h1f[VEC], h2f[VEC];
    int t = threadIdx.x;
    for (int i = t; i < VEC; i += 128) {
        s0[i] = misc[128 + i]; s1[i] = misc[480 + i];
        h1f[i] = misc[832 + i]; h2f[i] = misc[1536 + i];
    }
    __syncthreads();
    int j = blockIdx.x * 128 + t;
    if (j >= GATES) return;
    if (mode == 0) {
        float a = bihf[j] + bhhf[j];
        const float* w = wihf + (size_t)j * VEC;
        for (int k = 0; k < VEC; k += 4)
            a += w[k] * s0[k] + w[k + 1] * s0[k + 1] + w[k + 2] * s0[k + 2] + w[k + 3] * s0[k + 3];
        misc[2240 + j] = a;
    } else if (mode == 1) {
        float a = bihf[j] + bhhf[j];
        const float* w = wihf + (size_t)j * VEC;
        const float* wh = whhf + (size_t)j * VEC;
        for (int k = 0; k < VEC; k += 4) {
            a += w[k] * s1[k] + w[k + 1] * s1[k + 1] + w[k + 2] * s1[k + 2] + w[k + 3] * s1[k + 3];
            a += wh[k] * h1f[k] + wh[k + 1] * h1f[k + 1] + wh[k + 2] * h1f[k + 2] + wh[k + 3] * h1f[k + 3];
        }
        misc[3648 + j] = a;
    } else {
        float a = bihf[j] + bhhf[j];
        const float* wh = whhf + (size_t)j * VEC;
        for (int k = 0; k < VEC; k += 4)
            a += wh[k] * h2f[k] + wh[k + 1] * h2f[k + 1] + wh[k + 2] * h2f[k + 2] + wh[k + 3] * h2f[k + 3];
        misc[5056 + j] = a;                     // gf_const
        float br = bihr[j] + bhhr[j];
        const float* wr = wihr + (size_t)j * VEC;
        float p1 = br, p0 = br;
        for (int k = 0; k < VEC; k += 4) {
            p1 += wr[k] * s1[k] + wr[k + 1] * s1[k + 1] + wr[k + 2] * s1[k + 2] + wr[k + 3] * s1[k + 3];
            p0 += wr[k] * s0[k] + wr[k + 1] * s0[k + 1] + wr[k + 2] * s0[k + 2] + wr[k + 3] * s0[k + 3];
        }
        misc[6464 + j] = p1;                    // pre_s1
        misc[7872 + j] = p0;                    // pre_s0
    }
}

__global__ void cell_small(const float* __restrict__ g, const float* __restrict__ cp,
    float* __restrict__ ho, float* __restrict__ co)
{
    int h = blockIdx.x * 64 + threadIdx.x;
    if (h >= HID) return;
    float iv = sigf(g[h]), fv = sigf(g[HID + h]);
    float gv = tanhf(g[2 * HID + h]), ov = sigf(g[3 * HID + h]);
    float c = iv * gv + (cp ? fv * cp[h] : 0.f);
    ho[h] = ov * tanhf(c);
    co[h] = c;
}

// ---------------- big LSTM step: bf16 MFMA GEMM + fused cell (split-kernel, no spill) ----------------
// Block 256 threads = 4 waves; wave handles 64 q x 16 h. X is MFMA A-operand, W rows the B-operand.
// cmode: 0 -> cprev=0 ; 1 -> cprev=cprevf[h] (const f32 vec) ; 2 -> cprev=cprevb[q*HID+h] (bf16)
// Outputs: h bf16 always; c bf16 optional. (f32 h/c round-trips removed vs round-3: -46MB/dispatch)
__global__ __launch_bounds__(256) void lstm_mfma(
    const unsigned short* __restrict__ Xb, const unsigned short* __restrict__ Wb,
    const float* __restrict__ add1, const float* __restrict__ add2,
    const float* __restrict__ cprevf, const unsigned short* __restrict__ cprevb, int cmode,
    unsigned short* __restrict__ hbf, unsigned short* __restrict__ cbf, int Q)
{
    int t = threadIdx.x, wv = t >> 6, lane = t & 63;
    int li = lane & 15, grp = lane >> 4;
    int q0 = blockIdx.x * 256 + wv * 64;
    int h0 = blockIdx.y * 16;
    int h = h0 + li;
    const unsigned short* xp[4];
#pragma unroll
    for (int mf = 0; mf < 4; ++mf) {
        int qr = q0 + mf * 16 + li;
        if (qr > Q - 1) qr = Q - 1;
        xp[mf] = Xb + (size_t)qr * VEC + grp * 8;
    }
    const unsigned short* wbase = Wb + (size_t)(h0 + li) * VEC + grp * 8;
    float4v acc[4][4];
#pragma unroll
    for (int gi = 0; gi < 4; ++gi)
#pragma unroll
        for (int mf = 0; mf < 4; ++mf) acc[gi][mf] = (float4v){0.f, 0.f, 0.f, 0.f};
#pragma unroll 2
    for (int ks = 0; ks < 11; ++ks) {
        int ko = ks * 32;
        short8v a0 = *(const short8v*)(xp[0] + ko);
        short8v a1 = *(const short8v*)(xp[1] + ko);
        short8v a2 = *(const short8v*)(xp[2] + ko);
        short8v a3 = *(const short8v*)(xp[3] + ko);
        short8v b0 = *(const short8v*)(wbase + ko);
        short8v b1 = *(const short8v*)(wbase + (size_t)HID * VEC + ko);
        short8v b2 = *(const short8v*)(wbase + (size_t)2 * HID * VEC + ko);
        short8v b3 = *(const short8v*)(wbase + (size_t)3 * HID * VEC + ko);
        acc[0][0] = __builtin_amdgcn_mfma_f32_16x16x32_bf16(a0, b0, acc[0][0], 0, 0, 0);
        acc[0][1] = __builtin_amdgcn_mfma_f32_16x16x32_bf16(a1, b0, acc[0][1], 0, 0, 0);
        acc[0][2] = __builtin_amdgcn_mfma_f32_16x16x32_bf16(a2, b0, acc[0][2], 0, 0, 0);
        acc[0][3] = __builtin_amdgcn_mfma_f32_16x16x32_bf16(a3, b0, acc[0][3], 0, 0, 0);
        acc[1][0] = __builtin_amdgcn_mfma_f32_16x16x32_bf16(a0, b1, acc[1][0], 0, 0, 0);
        acc[1][1] = __builtin_amdgcn_mfma_f32_16x16x32_bf16(a1, b1, acc[1][1], 0, 0, 0);
        acc[1][2] = __builtin_amdgcn_mfma_f32_16x16x32_bf16(a2, b1, acc[1][2], 0, 0, 0);
        acc[1][3] = __builtin_amdgcn_mfma_f32_16x16x32_bf16(a3, b1, acc[1][3], 0, 0, 0);
        acc[2][0] = __builtin_amdgcn_mfma_f32_16x16x32_bf16(a0, b2, acc[2][0], 0, 0, 0);
        acc[2][1] = __builtin_amdgcn_mfma_f32_16x16x32_bf16(a1, b2, acc[2][1], 0, 0, 0);
        acc[2][2] = __builtin_amdgcn_mfma_f32_16x16x32_bf16(a2, b2, acc[2][2], 0, 0, 0);
        acc[2][3] = __builtin_amdgcn_mfma_f32_16x16x32_bf16(a3, b2, acc[2][3], 0, 0, 0);
        acc[3][0] = __builtin_amdgcn_mfma_f32_16x16x32_bf16(a0, b3, acc[3][0], 0, 0, 0);
        acc[3][1] = __builtin_amdgcn_mfma_f32_16x16x32_bf16(a1, b3, acc[3][1], 0, 0, 0);
        acc[3][2] = __builtin_amdgcn_mfma_f32_16x16x32_bf16(a2, b3, acc[3][2], 0, 0, 0);
        acc[3][3] = __builtin_amdgcn_mfma_f32_16x16x32_bf16(a3, b3, acc[3][3], 0, 0, 0);
    }
    float ai = add1[h] + (add2 ? add2[h] : 0.f);
    float afv = add1[HID + h] + (add2 ? add2[HID + h] : 0.f);
    float ag = add1[2 * HID + h] + (add2 ? add2[2 * HID + h] : 0.f);
    float ao = add1[3 * HID + h] + (add2 ? add2[3 * HID + h] : 0.f);
    float cc1 = (cmode == 1) ? cprevf[h] : 0.f;
#pragma unroll
    for (int mf = 0; mf < 4; ++mf) {
#pragma unroll
        for (int r = 0; r < 4; ++r) {
            int q = q0 + mf * 16 + grp * 4 + r;
            if (q >= Q) continue;
            float iv = sigf(acc[0][mf][r] + ai);
            float fv = sigf(acc[1][mf][r] + afv);
            float gv = ftanh(acc[2][mf][r] + ag);
            float ov = sigf(acc[3][mf][r] + ao);
            float cp = (cmode == 2) ? bf2f(cprevb[(size_t)q * HID + h]) : cc1;
            float cn = fv * cp + iv * gv;
            float hn = ov * ftanh(cn);
            hbf[(size_t)q * HID + h] = f2bf(hn);
            if (cbf) cbf[(size_t)q * HID + h] = f2bf(cn);
        }
    }
}

// ---------------- cosine sims + softmax; one wave per query (bf16 h inputs) ----------------
__global__ __launch_bounds__(256) void final_sims(
    const unsigned short* __restrict__ h3f, const unsigned short* __restrict__ hb1,
    const unsigned short* __restrict__ hb2, const unsigned short* __restrict__ hb3,
    const float* __restrict__ misc, float* __restrict__ out, int Q)
{
    int t = threadIdx.x;
    int wave = t >> 6, lane = t & 63;
    int q = blockIdx.x * 4 + wave;
    if (q >= Q) return;
    const unsigned short* a3 = h3f + (size_t)q * HID;
    const unsigned short* b1 = hb1 + (size_t)q * HID;
    const unsigned short* b2 = hb2 + (size_t)q * HID;
    const unsigned short* b3 = hb3 + (size_t)q * HID;
    const float* h1c = misc + 832;
    const float* h2c = misc + 1536;
    float sA = 0, sB = 0, s3 = 0, s4 = 0, s5 = 0, s6 = 0, s7 = 0, s8 = 0, s9 = 0, s10 = 0;
    for (int hh = lane; hh < HID; hh += 64) {
        float a = bf2f(a3[hh]), b = bf2f(b1[hh]), v2 = bf2f(b2[hh]), v3 = bf2f(b3[hh]);
        float u1 = h1c[hh], u2 = h2c[hh];
        sA += u1 * a;  sB += u2 * a;
        s3 += a * a;   s4 += b * b;
        s5 += v3 * b;  s6 += v2 * b;
        s7 += v3 * v3; s8 += v2 * v2;
        s9 += u1 * u1; s10 += u2 * u2;
    }
#pragma unroll
    for (int off = 32; off > 0; off >>= 1) {
        sA += __shfl_xor(sA, off);  sB += __shfl_xor(sB, off);
        s3 += __shfl_xor(s3, off);  s4 += __shfl_xor(s4, off);
        s5 += __shfl_xor(s5, off);  s6 += __shfl_xor(s6, off);
        s7 += __shfl_xor(s7, off);  s8 += __shfl_xor(s8, off);
        s9 += __shfl_xor(s9, off);  s10 += __shfl_xor(s10, off);
    }
    if (lane == 0) {
        float nq  = fmaxf(sqrtf(s3 + s4), 1e-8f);
        float ns0 = fmaxf(sqrtf(s9 + s7), 1e-8f);
        float ns1 = fmaxf(sqrtf(s10 + s8), 1e-8f);
        float sim0 = (sA + s5) / (ns0 * nq);
        float sim1 = (sB + s6) / (ns1 * nq);
        float mx = fmaxf(sim0, sim1);
        float e0 = __expf(sim0 - mx), e1 = __expf(sim1 - mx);
        float inv = 1.f / (e0 + e1);
        out[(size_t)q * 2 + 0] = e0 * inv;
        out[(size_t)q * 2 + 1] = e1 * inv;
    }
}

extern "C" void kernel_launch(void* const* d_in, const int* in_sizes, int n_in,
                              void* d_out, int out_size, void* d_ws, size_t ws_size,
                              hipStream_t stream)
{
    const float* x    = (const float*)d_in[0];
    const float* c1w  = (const float*)d_in[1];
    const float* c1b  = (const float*)d_in[2];
    const float* bn1g = (const float*)d_in[3];
    const float* bn1b = (const float*)d_in[4];
    const float* c2w  = (const float*)d_in[5];
    const float* c2b  = (const float*)d_in[6];
    const float* bn2g = (const float*)d_in[7];
    const float* bn2b = (const float*)d_in[8];
    const float* wihf = (const float*)d_in[9];
    const float* whhf = (const float*)d_in[10];
    const float* bihf = (const float*)d_in[11];
    const float* bhhf = (const float*)d_in[12];
    const float* wihr = (const float*)d_in[13];
    const float* whhr = (const float*)d_in[14];
    const float* bihr = (const float*)d_in[15];
    const float* bhhr = (const float*)d_in[16];

    int N = in_sizes[0] / LIN;
    int Q = N - NSUP;

    char* ws = (char*)d_ws;
    float* part1 = (float*)(ws + 0);                       // 2048*64 f32
    float* part2 = (float*)(ws + 524288);
    float* misc  = (float*)(ws + 1048576);                 // ~10.7K f32
    unsigned short* w2t = (unsigned short*)(ws + 1114112); // 5120 bf16
    unsigned short* Wf  = (unsigned short*)(ws + 2097152); // 1408*352 bf16
    unsigned short* Wr  = (unsigned short*)(ws + 3145728);
    unsigned short* Wh  = (unsigned short*)(ws + 4194304);
    unsigned short* z   = (unsigned short*)(ws + 5242880); // N*352 bf16
    unsigned short* h1  = (unsigned short*)(ws + 17825792);// N*64*32 bf16 (dead after conv2)
    const size_t Sb = (size_t)Q * HID * sizeof(unsigned short);   // ~11.5MB
    unsigned short* h3fb = (unsigned short*)(ws + 17825792);      // over h1 (dead)
    unsigned short* hb1b = (unsigned short*)(ws + 17825792 + Sb);
    unsigned short* cb1b = (unsigned short*)(ws + 17825792 + 2 * Sb);
    unsigned short* hb2b = (unsigned short*)(ws + 17825792 + 3 * Sb);
    unsigned short* cb2b = (unsigned short*)(ws + 17825792 + 4 * Sb);
    unsigned short* hb3b = (unsigned short*)(ws + 17825792 + 5 * Sb);

    // 1. cast weights
    {
        int tot = 3 * GATES * VEC + 5120;
        cast_weights<<<(tot + 255) / 256, 256, 0, stream>>>(wihf, wihr, whhr, c2w, Wf, Wr, Wh, w2t);
    }
    // 2. conv1: stats + pooled raw
    conv1_pass1<<<NBLK, 256, 0, stream>>>(x, c1w, c1b, part1, h1, N);
    finalize_stats2<<<1, 512, 0, stream>>>(part1, misc + 0, misc + 32, (float)((long long)N * L1C));
    // 3. conv1 BN+relu in place
    {
        long long total = (long long)N * 236;
        conv1_pass2<<<(unsigned)((total + 255) / 256), 256, 0, stream>>>(h1, misc + 0, misc + 32, bn1g, bn1b, total);
    }
    // 4. conv2 stats
    conv2_stats_mfma<<<NBLK, 256, 0, stream>>>(h1, w2t, c2b, part2, N);
    finalize_stats2<<<1, 512, 0, stream>>>(part2, misc + 64, misc + 96, (float)((long long)N * L2C));
    // 5. conv2 apply -> z
    conv2_apply_mfma<<<NBLK, 256, 0, stream>>>(h1, w2t, c2b, misc + 64, misc + 96, bn2g, bn2b, z, N);
    // 6. support path
    sup_means<<<6, 64, 0, stream>>>(z, misc);
    gates_gemv<<<11, 128, 0, stream>>>(0, wihf, whhf, bihf, bhhf, wihr, bihr, bhhr, misc);
    cell_small<<<6, 64, 0, stream>>>(misc + 2240, nullptr, misc + 832, misc + 1184);
    gates_gemv<<<11, 128, 0, stream>>>(1, wihf, whhf, bihf, bhhf, wihr, bihr, bhhr, misc);
    cell_small<<<6, 64, 0, stream>>>(misc + 3648, misc + 1184, misc + 1536, misc + 1888);
    gates_gemv<<<11, 128, 0, stream>>>(2, wihf, whhf, bihf, bhhf, wihr, bihr, bhhr, misc);
    // 7. big LSTM steps (bf16 h/c state)
    const unsigned short* zq = z + (size_t)NSUP * VEC;
    dim3 gg((Q + 255) / 256, 22);
    // fwd step2: gates = zq@Wf + gf_const ; cprev = c2f (const f32 vec)
    lstm_mfma<<<gg, 256, 0, stream>>>(zq, Wf, misc + 5056, nullptr, misc + 1888, nullptr, 1, h3fb, nullptr, Q);
    // bwd step0: gates = zq@Wr + (bihr+bhhr) ; cprev = 0
    lstm_mfma<<<gg, 256, 0, stream>>>(zq, Wr, bihr, bhhr, nullptr, nullptr, 0, hb1b, cb1b, Q);
    // bwd step1: gates = hb1@Wh + pre_s1 ; cprev = cb1 (bf16)
    lstm_mfma<<<gg, 256, 0, stream>>>(hb1b, Wh, misc + 6464, nullptr, nullptr, cb1b, 2, hb2b, cb2b, Q);
    // bwd step2: gates = hb2@Wh + pre_s0 ; cprev = cb2 (bf16)
    lstm_mfma<<<gg, 256, 0, stream>>>(hb2b, Wh, misc + 7872, nullptr, nullptr, cb2b, 2, hb3b, nullptr, Q);
    // 8. sims + softmax
    final_sims<<<(Q + 3) / 4, 256, 0, stream>>>(h3fb, hb1b, hb2b, hb3b, misc, (float*)d_out, Q);
}